// Round 3
// baseline (1026.829 us; speedup 1.0000x reference)
//
#include <hip/hip_runtime.h>
#include <hip/hip_bf16.h>

// ---------------------------------------------------------------------------
// ONE persistent mega-kernel (512 blocks x 256 thr, 2 blocks/CU co-resident)
// with device-scope atomic grid barriers between phases:
//  P1 gemm1 (fp32, split-K 8)   P2 reduce+lrelu -> h1
//  P3 gemm2 (fp32, split-K 16)  P4 reduce+lrelu -> h2
//  P5 gemm3 (fp32, split-K 16)  P6 reduce+lrelu -> feat[:,0:1024] + h3 bf16
//  P7 gemm4 (bf16 MFMA 16x16x32, K-split 2) -> accM bf16[2][128][10240]
//  P8 pairwise (o_b) -> feat[:,1024:]   P9 final dot -> out
// Barrier: monotone epoch counter in ws[0..1024), zeroed by a hipMemsetAsync
// node each call (ws is re-poisoned to 0xAA by the harness before every run).
// ws layout (bytes):
//   [0, 1024)            barrier counter
//   [1024, ~8.4M)        P    fp32 split-K partials (max 16x128x1024)
//   [16M, 21.3M)         accM bf16[2][128][10240]
//   [26M, 27M)           h1   128x2048 f32
//   [28M, 28.5M)         h2   128x1024 f32
//   [29M, 29.25M)        h3b  128x1024 bf16
//   [30M, 30.75M)        feat 128x1536 f32
// ---------------------------------------------------------------------------

typedef __bf16 bf16x8 __attribute__((ext_vector_type(8)));
typedef float  f32x4  __attribute__((ext_vector_type(4)));

#define NB 512   // grid size; capacity = 256 CU x >=2 blocks/CU >= 1024, safe

static __device__ __forceinline__ unsigned int f2bf(float f) {
  union { float f; unsigned int u; } v; v.f = f;
  unsigned int r = v.u + 0x7FFFu + ((v.u >> 16) & 1u);   // RNE to bf16
  return r >> 16;
}
static __device__ __forceinline__ float bf2f(unsigned short u) {
  union { unsigned int u; float f; } v; v.u = ((unsigned int)u) << 16;
  return v.f;
}
static __device__ __forceinline__ float lrelu(float x) {
  return x >= 0.0f ? x : 0.01f * x;
}
static __device__ __forceinline__ void fma4(float4& c, float a, const float4& w) {
  c.x = fmaf(a, w.x, c.x); c.y = fmaf(a, w.y, c.y);
  c.z = fmaf(a, w.z, c.z); c.w = fmaf(a, w.w, c.w);
}

// Grid barrier: monotone counter, epoch e complete when cnt >= e*NB.
static __device__ __forceinline__ void grid_bar(unsigned int* cnt, unsigned int ep) {
  __threadfence();          // release: make this block's writes device-visible
  __syncthreads();
  if (threadIdx.x == 0) {
    atomicAdd(cnt, 1u);
    const unsigned int tgt = ep * (unsigned int)NB;
    while (atomicAdd(cnt, 0u) < tgt) __builtin_amdgcn_s_sleep(2);
  }
  __syncthreads();
  __threadfence();          // acquire: invalidate caches before reading remote data
}

// fp32 GEMM phase: tile 128 x 32, micro 4x4, register-prefetch double buffer.
// P_out already offset to this block's K-split slice.
static __device__ void gemm_f32_ph(
    const float* __restrict__ A, const float* __restrict__ W,
    float* __restrict__ P_out, int lda, int N, int kchunk, int kbase, int c0,
    float* As /*16x128*/, float* Ws /*16x32*/)
{
  const int t    = threadIdx.x;
  const int rowg = t >> 3, colg = t & 7;
  const int r_s  = t >> 1, kh_s = (t & 1) * 8;
  const int kw_s = t >> 4, f_s  = (t & 15) * 2;

  float4 acc[4];
  acc[0] = make_float4(0, 0, 0, 0); acc[1] = make_float4(0, 0, 0, 0);
  acc[2] = make_float4(0, 0, 0, 0); acc[3] = make_float4(0, 0, 0, 0);

  const float* aptr = A + (size_t)r_s * lda + kbase + kh_s;
  const float* wptr = W + (size_t)(kbase + kw_s) * N + c0 + f_s;
  float4 pa0 = *(const float4*)aptr;
  float4 pa1 = *(const float4*)(aptr + 4);
  float2 pw  = *(const float2*)wptr;

  for (int kt = 0; kt < kchunk; kt += 16) {
    As[(kh_s + 0) * 128 + r_s] = pa0.x; As[(kh_s + 1) * 128 + r_s] = pa0.y;
    As[(kh_s + 2) * 128 + r_s] = pa0.z; As[(kh_s + 3) * 128 + r_s] = pa0.w;
    As[(kh_s + 4) * 128 + r_s] = pa1.x; As[(kh_s + 5) * 128 + r_s] = pa1.y;
    As[(kh_s + 6) * 128 + r_s] = pa1.z; As[(kh_s + 7) * 128 + r_s] = pa1.w;
    *(float2*)(Ws + kw_s * 32 + f_s) = pw;
    __syncthreads();
    if (kt + 16 < kchunk) {
      aptr += 16;
      wptr += (size_t)16 * N;
      pa0 = *(const float4*)aptr;
      pa1 = *(const float4*)(aptr + 4);
      pw  = *(const float2*)wptr;
    }
    #pragma unroll
    for (int k = 0; k < 16; k++) {
      float4 w = *(const float4*)(Ws + k * 32 + colg * 4);
      float4 a = *(const float4*)(As + k * 128 + rowg * 4);
      fma4(acc[0], a.x, w); fma4(acc[1], a.y, w);
      fma4(acc[2], a.z, w); fma4(acc[3], a.w, w);
    }
    __syncthreads();
  }

  float* op = P_out + (size_t)(rowg * 4) * N + c0 + colg * 4;
  *(float4*)op           = acc[0];
  *(float4*)(op + N)     = acc[1];
  *(float4*)(op + 2 * N) = acc[2];
  *(float4*)(op + 3 * N) = acc[3];
}

// Sum S split-K partials + bias + LeakyReLU (+ optional bf16 copy).
static __device__ void reduce_ph(
    const float* __restrict__ P, const float* __restrict__ bias,
    float* __restrict__ outF, unsigned short* __restrict__ outB,
    int N, int S, int ldo, int gid)
{
  const int c4n = N >> 2;
  const int r   = gid / c4n;
  const int c   = (gid - r * c4n) * 4;
  float4 s = make_float4(0, 0, 0, 0);
  for (int si = 0; si < S; si++) {
    float4 p = *(const float4*)(P + (size_t)si * 128 * N + (size_t)r * N + c);
    s.x += p.x; s.y += p.y; s.z += p.z; s.w += p.w;
  }
  float4 b = *(const float4*)(bias + c);
  s.x = lrelu(s.x + b.x); s.y = lrelu(s.y + b.y);
  s.z = lrelu(s.z + b.z); s.w = lrelu(s.w + b.w);
  *(float4*)(outF + (size_t)r * ldo + c) = s;
  if (outB) {
    ushort4 u;
    u.x = (unsigned short)f2bf(s.x); u.y = (unsigned short)f2bf(s.y);
    u.z = (unsigned short)f2bf(s.z); u.w = (unsigned short)f2bf(s.w);
    *(ushort4*)(outB + (size_t)r * N + c) = u;
  }
}

// gemm4 phase: M = h3(bf16) @ T(f32->bf16), MFMA 16x16x32, tile 128x64,
// 16 k-tiles of 32 (kchunk 512). accM_out already offset to K-split slice.
static __device__ void gemm4_ph(
    const unsigned short* __restrict__ h3b, const float* __restrict__ T,
    unsigned short* __restrict__ accM_out, int c0, int kbase,
    unsigned short* Asm /*128x40*/, unsigned int* Wst /*64x20*/)
{
  const int t    = threadIdx.x;
  const int lane = t & 63, wave = t >> 6;
  const int ml   = lane & 15, q = lane >> 4;
  const int r0   = wave * 32;
  const int ra = t >> 2, qa = t & 3;
  const int kp = t & 15, n4 = (t >> 4) * 4;

  f32x4 acc[2][4];
  #pragma unroll
  for (int i = 0; i < 2; i++)
    #pragma unroll
    for (int j = 0; j < 4; j++) acc[i][j] = (f32x4){0.f, 0.f, 0.f, 0.f};

  const unsigned short* ap = h3b + (size_t)ra * 1024 + kbase + qa * 8;
  const float*          tp = T + (size_t)(kbase + 2 * kp) * 10240 + c0 + n4;
  uint4  va0 = *(const uint4*)ap;
  uint4  va1 = *(const uint4*)(ap + 64 * 1024);
  float4 vw0 = *(const float4*)tp;
  float4 vw1 = *(const float4*)(tp + 10240);

  for (int kt = 0; kt < 16; kt++) {
    *(uint4*)(Asm + ra * 40 + qa * 8)        = va0;
    *(uint4*)(Asm + (ra + 64) * 40 + qa * 8) = va1;
    Wst[(n4 + 0) * 20 + kp] = f2bf(vw0.x) | (f2bf(vw1.x) << 16);
    Wst[(n4 + 1) * 20 + kp] = f2bf(vw0.y) | (f2bf(vw1.y) << 16);
    Wst[(n4 + 2) * 20 + kp] = f2bf(vw0.z) | (f2bf(vw1.z) << 16);
    Wst[(n4 + 3) * 20 + kp] = f2bf(vw0.w) | (f2bf(vw1.w) << 16);
    __syncthreads();
    if (kt < 15) {
      ap += 32;
      tp += (size_t)32 * 10240;
      va0 = *(const uint4*)ap;
      va1 = *(const uint4*)(ap + 64 * 1024);
      vw0 = *(const float4*)tp;
      vw1 = *(const float4*)(tp + 10240);
    }
    bf16x8 a0 = *(const bf16x8*)(Asm + (r0 + ml) * 40 + q * 8);
    bf16x8 a1 = *(const bf16x8*)(Asm + (r0 + 16 + ml) * 40 + q * 8);
    #pragma unroll
    for (int ct = 0; ct < 4; ct++) {
      bf16x8 b = *(const bf16x8*)((const unsigned short*)Wst +
                                  (size_t)((ct * 16 + ml) * 20 + q * 4) * 2);
      acc[0][ct] = __builtin_amdgcn_mfma_f32_16x16x32_bf16(a0, b, acc[0][ct], 0, 0, 0);
      acc[1][ct] = __builtin_amdgcn_mfma_f32_16x16x32_bf16(a1, b, acc[1][ct], 0, 0, 0);
    }
    __syncthreads();
  }

  // C/D layout: col = lane&15, row = (lane>>4)*4 + reg
  #pragma unroll
  for (int rt = 0; rt < 2; rt++)
    #pragma unroll
    for (int ct = 0; ct < 4; ct++) {
      int col = c0 + ct * 16 + ml;
      int row = r0 + rt * 16 + q * 4;
      #pragma unroll
      for (int i = 0; i < 4; i++)
        accM_out[(size_t)(row + i) * 10240 + col] = (unsigned short)f2bf(acc[rt][ct][i]);
    }
}

// pairwise phase: one block per o; 256 thr: 128 j (2/thr) x 4 i-strips of 32.
static __device__ void pw_ph(
    const unsigned short* __restrict__ accM, float* __restrict__ feat, int o,
    float* Ml /*128x20*/, float* parts /*4x128*/)
{
  const int t = threadIdx.x;
  { // combine 2 K-splits: M[:, o, :]
    int i = t >> 1, kh = (t & 1) * 10;
    const unsigned short* p = accM + (size_t)i * 10240 + o * 20 + kh;
    #pragma unroll
    for (int k = 0; k < 10; k++)
      Ml[i * 20 + kh + k] = bf2f(p[k]) + bf2f(p[1310720 + k]);
  }
  __syncthreads();

  const int jg = t & 63, istrip = t >> 6;
  float mj[2][20];
  #pragma unroll
  for (int c = 0; c < 2; c++) {
    const float* src = Ml + (size_t)(jg * 2 + c) * 20;
    #pragma unroll
    for (int k = 0; k < 20; k++) mj[c][k] = src[k];
  }
  float acc[2] = {0.f, 0.f};
  for (int ii = 0; ii < 32; ii++) {
    int i = istrip * 32 + ii;
    const float4* m4 = (const float4*)(Ml + (size_t)i * 20);
    float mi[20];
    *(float4*)(mi + 0)  = m4[0]; *(float4*)(mi + 4)  = m4[1];
    *(float4*)(mi + 8)  = m4[2]; *(float4*)(mi + 12) = m4[3];
    *(float4*)(mi + 16) = m4[4];
    #pragma unroll
    for (int c = 0; c < 2; c++) {
      float norm = 0.f;
      #pragma unroll
      for (int k = 0; k < 20; k++) norm += fabsf(mi[k] - mj[c][k]);
      acc[c] += __expf(-norm);
    }
  }
  #pragma unroll
  for (int c = 0; c < 2; c++) parts[istrip * 128 + jg * 2 + c] = acc[c];
  __syncthreads();
  if (t < 128) {
    float s = 0.f;
    #pragma unroll
    for (int ih = 0; ih < 4; ih++) s += parts[ih * 128 + t];
    feat[(size_t)t * 1536 + 1024 + o] = s - 1.0f;   // subtract self-term
  }
}

// final phase: out[r] = feat[r,:] . Wc + bc
static __device__ void fin_ph(
    const float* __restrict__ feat, const float* __restrict__ Wc,
    const float* __restrict__ bc, float* __restrict__ out, int r, float* red)
{
  const int t = threadIdx.x;
  float s = 0.f;
  for (int c = t; c < 1536; c += 256) s += feat[(size_t)r * 1536 + c] * Wc[c];
  for (int off = 32; off > 0; off >>= 1) s += __shfl_down(s, off);
  if ((t & 63) == 0) red[t >> 6] = s;
  __syncthreads();
  if (t == 0) out[r] = red[0] + red[1] + red[2] + red[3] + bc[0];
}

// ---------------------------------------------------------------------------
__global__ __launch_bounds__(256, 2) void mega(
    const float* __restrict__ X,
    const float* __restrict__ W1, const float* __restrict__ b1,
    const float* __restrict__ W2, const float* __restrict__ b2,
    const float* __restrict__ W3, const float* __restrict__ b3,
    const float* __restrict__ T,  const float* __restrict__ Wc,
    const float* __restrict__ bc, float* __restrict__ out, char* ws)
{
  __shared__ __align__(16) char smem[16384];
  unsigned int*   cnt  = (unsigned int*)ws;
  float*          P    = (float*)(ws + 1024);
  unsigned short* accM = (unsigned short*)(ws + (size_t)16 * 1024 * 1024);
  float*          h1   = (float*)(ws + (size_t)26 * 1024 * 1024);
  float*          h2   = (float*)(ws + (size_t)28 * 1024 * 1024);
  unsigned short* h3b  = (unsigned short*)(ws + (size_t)29 * 1024 * 1024);
  float*          feat = (float*)(ws + (size_t)30 * 1024 * 1024);

  float*          As   = (float*)smem;                    // 8 KB
  float*          Ws   = (float*)(smem + 8192);           // 2 KB
  unsigned short* Asm  = (unsigned short*)smem;           // 10 KB
  unsigned int*   Wst  = (unsigned int*)(smem + 10240);   // 5 KB
  float*          Ml   = (float*)smem;                    // 10 KB
  float*          parts= (float*)(smem + 10240);          // 2 KB
  float*          red  = (float*)smem;

  const int bid = blockIdx.x;
  const int t   = threadIdx.x;
  unsigned int ep = 0;

  // P1: gemm1  [128,2048] += X @ W1, split-K 8 (64 col-tiles x 8)
  gemm_f32_ph(X, W1, P + (size_t)(bid & 7) * 128 * 2048, 2048, 2048, 256,
              (bid & 7) * 256, (bid >> 3) * 32, As, Ws);
  grid_bar(cnt, ++ep);
  // P2: h1 = lrelu(sum + b1)
  { int gid = bid * 256 + t;
    if (gid < 65536) reduce_ph(P, b1, h1, nullptr, 2048, 8, 2048, gid); }
  grid_bar(cnt, ++ep);
  // P3: gemm2  [128,1024] = h1 @ W2, split-K 16 (32 col-tiles x 16)
  gemm_f32_ph(h1, W2, P + (size_t)(bid & 15) * 128 * 1024, 2048, 1024, 128,
              (bid & 15) * 128, (bid >> 4) * 32, As, Ws);
  grid_bar(cnt, ++ep);
  // P4: h2 = lrelu(sum + b2)
  { int gid = bid * 256 + t;
    if (gid < 32768) reduce_ph(P, b2, h2, nullptr, 1024, 16, 1024, gid); }
  grid_bar(cnt, ++ep);
  // P5: gemm3  [128,1024] = h2 @ W3, split-K 16
  gemm_f32_ph(h2, W3, P + (size_t)(bid & 15) * 128 * 1024, 1024, 1024, 64,
              (bid & 15) * 64, (bid >> 4) * 32, As, Ws);
  grid_bar(cnt, ++ep);
  // P6: feat[:, :1024] = h3 = lrelu(sum + b3); also bf16 copy h3b
  { int gid = bid * 256 + t;
    if (gid < 32768) reduce_ph(P, b3, feat, h3b, 1024, 16, 1536, gid); }
  grid_bar(cnt, ++ep);
  // P7: gemm4  M = h3 @ T (bf16 MFMA), 160 col-tiles x K-split 2 = 320 blocks
  if (bid < 320)
    gemm4_ph(h3b, T, accM + (size_t)(bid & 1) * 128 * 10240,
             (bid >> 1) * 64, (bid & 1) * 512, Asm, Wst);
  grid_bar(cnt, ++ep);
  // P8: minibatch discrimination -> feat[:, 1024:]
  pw_ph(accM, feat, bid, Ml, parts);
  grid_bar(cnt, ++ep);
  // P9: out = feat @ Wc + bc
  if (bid < 128) fin_ph(feat, Wc, bc, out, bid, red);
}

// ---------------------------------------------------------------------------
extern "C" void kernel_launch(void* const* d_in, const int* in_sizes, int n_in,
                              void* d_out, int out_size, void* d_ws, size_t ws_size,
                              hipStream_t stream)
{
  const float* X  = (const float*)d_in[0];
  const float* W1 = (const float*)d_in[1];
  const float* b1 = (const float*)d_in[2];
  const float* W2 = (const float*)d_in[3];
  const float* b2 = (const float*)d_in[4];
  const float* W3 = (const float*)d_in[5];
  const float* b3 = (const float*)d_in[6];
  const float* T  = (const float*)d_in[7];
  const float* Wc = (const float*)d_in[8];
  const float* bc = (const float*)d_in[9];
  char* ws = (char*)d_ws;

  hipMemsetAsync(ws, 0, 1024, stream);   // barrier counter = 0 (graph memset node)
  mega<<<NB, 256, 0, stream>>>(X, W1, b1, W2, b2, W3, b3, T, Wc, bc,
                               (float*)d_out, ws);
}

// Round 4
// 447.003 us; speedup vs baseline: 2.2971x; 2.2971x over previous
//
#include <hip/hip_runtime.h>
#include <hip/hip_bf16.h>

// ---------------------------------------------------------------------------
// 4-kernel chain, no grid barriers, "last-block" fused epilogues:
//  K1 gemm1 fp32 splitK8  + last-block reduce(+b1,lrelu) -> h1
//  K2 gemm2 fp32 splitK16 + last-block reduce(+b2,lrelu) -> h2
//  K3 gemm3 fp32 splitK8  + last-block reduce(+b3,lrelu) -> feat[:,0:1024], h3b bf16
//  K4 gemm4 bf16 MFMA (coltile 64, K-split 2) -> accM bf16; per-o dependency
//     counters; finishing block computes pairwise for its o's -> feat[:,1024+o];
//     block bringing fin-counter to 512 computes final dot -> out.
// Flags zeroed by one hipMemsetAsync node per call.
// ws layout (bytes):
//   [0, 4096)       flags: f1[64]@0, f2[64]@256, f3[64]@512, ocnt[512]@1024, fin@3072
//   [1M, 9.4M)      P     fp32 split-K partials (max 16 x 128 x 1024)
//   [10M, 15.3M)    accM  bf16[2][128][10240]
//   [16M, 17M)      h1    128x2048 f32
//   [18M, 18.5M)    h2    128x1024 f32
//   [19M, 19.25M)   h3b   128x1024 bf16
//   [20M, 20.75M)   feat  128x1536 f32
// ---------------------------------------------------------------------------

typedef __bf16 bf16x8 __attribute__((ext_vector_type(8)));
typedef float  f32x4  __attribute__((ext_vector_type(4)));

static __device__ __forceinline__ unsigned int f2bf(float f) {
  union { float f; unsigned int u; } v; v.f = f;
  unsigned int r = v.u + 0x7FFFu + ((v.u >> 16) & 1u);   // RNE to bf16
  return r >> 16;
}
static __device__ __forceinline__ float bf2f(unsigned short u) {
  union { unsigned int u; float f; } v; v.u = ((unsigned int)u) << 16;
  return v.f;
}
static __device__ __forceinline__ float lrelu(float x) {
  return x >= 0.0f ? x : 0.01f * x;
}
static __device__ __forceinline__ void fma4(float4& c, float a, const float4& w) {
  c.x = fmaf(a, w.x, c.x); c.y = fmaf(a, w.y, c.y);
  c.z = fmaf(a, w.z, c.z); c.w = fmaf(a, w.w, c.w);
}

// fp32 GEMM tile 128x32, micro 4x4, register-prefetch double buffer.
static __device__ void gemm_f32_ph(
    const float* __restrict__ A, const float* __restrict__ W,
    float* __restrict__ P_out, int lda, int N, int kchunk, int kbase, int c0,
    float* As /*16x128*/, float* Ws /*16x32*/)
{
  const int t    = threadIdx.x;
  const int rowg = t >> 3, colg = t & 7;
  const int r_s  = t >> 1, kh_s = (t & 1) * 8;
  const int kw_s = t >> 4, f_s  = (t & 15) * 2;

  float4 acc[4];
  acc[0] = make_float4(0, 0, 0, 0); acc[1] = make_float4(0, 0, 0, 0);
  acc[2] = make_float4(0, 0, 0, 0); acc[3] = make_float4(0, 0, 0, 0);

  const float* aptr = A + (size_t)r_s * lda + kbase + kh_s;
  const float* wptr = W + (size_t)(kbase + kw_s) * N + c0 + f_s;
  float4 pa0 = *(const float4*)aptr;
  float4 pa1 = *(const float4*)(aptr + 4);
  float2 pw  = *(const float2*)wptr;

  for (int kt = 0; kt < kchunk; kt += 16) {
    As[(kh_s + 0) * 128 + r_s] = pa0.x; As[(kh_s + 1) * 128 + r_s] = pa0.y;
    As[(kh_s + 2) * 128 + r_s] = pa0.z; As[(kh_s + 3) * 128 + r_s] = pa0.w;
    As[(kh_s + 4) * 128 + r_s] = pa1.x; As[(kh_s + 5) * 128 + r_s] = pa1.y;
    As[(kh_s + 6) * 128 + r_s] = pa1.z; As[(kh_s + 7) * 128 + r_s] = pa1.w;
    *(float2*)(Ws + kw_s * 32 + f_s) = pw;
    __syncthreads();
    if (kt + 16 < kchunk) {
      aptr += 16;
      wptr += (size_t)16 * N;
      pa0 = *(const float4*)aptr;
      pa1 = *(const float4*)(aptr + 4);
      pw  = *(const float2*)wptr;
    }
    #pragma unroll
    for (int k = 0; k < 16; k++) {
      float4 w = *(const float4*)(Ws + k * 32 + colg * 4);
      float4 a = *(const float4*)(As + k * 128 + rowg * 4);
      fma4(acc[0], a.x, w); fma4(acc[1], a.y, w);
      fma4(acc[2], a.z, w); fma4(acc[3], a.w, w);
    }
    __syncthreads();
  }

  float* op = P_out + (size_t)(rowg * 4) * N + c0 + colg * 4;
  *(float4*)op           = acc[0];
  *(float4*)(op + N)     = acc[1];
  *(float4*)(op + 2 * N) = acc[2];
  *(float4*)(op + 3 * N) = acc[3];
}

// Last-block epilogue: sum S partial slices of 32 cols + bias + lrelu.
// 256 thr: row = t>>1 (128 rows), 16 cols = 4 float4 at c0 + (t&1)*16.
static __device__ void tile_reduce(
    const float* __restrict__ P, const float* __restrict__ bias,
    float* __restrict__ outF, unsigned short* __restrict__ outB,
    int N, int S, int c0, int ldo)
{
  const int t   = threadIdx.x;
  const int row = t >> 1;
  const int cb  = c0 + (t & 1) * 16;
  float4 acc[4];
  acc[0] = make_float4(0, 0, 0, 0); acc[1] = make_float4(0, 0, 0, 0);
  acc[2] = make_float4(0, 0, 0, 0); acc[3] = make_float4(0, 0, 0, 0);
  for (int s = 0; s < S; s++) {
    const float* p = P + (size_t)s * 128 * N + (size_t)row * N + cb;
    #pragma unroll
    for (int j = 0; j < 4; j++) {
      float4 v = *(const float4*)(p + 4 * j);
      acc[j].x += v.x; acc[j].y += v.y; acc[j].z += v.z; acc[j].w += v.w;
    }
  }
  #pragma unroll
  for (int j = 0; j < 4; j++) {
    float4 b = *(const float4*)(bias + cb + 4 * j);
    float4 r;
    r.x = lrelu(acc[j].x + b.x); r.y = lrelu(acc[j].y + b.y);
    r.z = lrelu(acc[j].z + b.z); r.w = lrelu(acc[j].w + b.w);
    *(float4*)(outF + (size_t)row * ldo + cb + 4 * j) = r;
    if (outB) {
      ushort4 u;
      u.x = (unsigned short)f2bf(r.x); u.y = (unsigned short)f2bf(r.y);
      u.z = (unsigned short)f2bf(r.z); u.w = (unsigned short)f2bf(r.w);
      *(ushort4*)(outB + (size_t)row * 1024 + cb + 4 * j) = u;
    }
  }
}

// One fp32 layer: split-K gemm + last-arriving-block fused reduce epilogue.
__global__ __launch_bounds__(256, 4) void k_layer(
    const float* __restrict__ A, const float* __restrict__ W,
    const float* __restrict__ bias, float* __restrict__ P,
    float* __restrict__ outF, unsigned short* __restrict__ outB,
    unsigned int* __restrict__ flag, int lda, int N, int kchunk, int S, int ldo)
{
  __shared__ __align__(16) float As[16 * 128];
  __shared__ __align__(16) float Ws[16 * 32];
  __shared__ unsigned int old;
  const int c  = blockIdx.x, s = blockIdx.y;
  const int c0 = c * 32;

  gemm_f32_ph(A, W, P + (size_t)s * 128 * N, lda, N, kchunk, s * kchunk, c0, As, Ws);

  __threadfence();                 // release this block's partial stores
  __syncthreads();
  if (threadIdx.x == 0) old = atomicAdd(&flag[c], 1u);
  __syncthreads();
  if (old == (unsigned int)(S - 1)) {
    __threadfence();               // acquire other blocks' partials
    tile_reduce(P, bias, outF, outB, N, S, c0, ldo);
  }
}

// gemm4 MFMA phase: tile 128x64 over K-chunk 512 (16 k-tiles of 32).
static __device__ void gemm4_ph(
    const unsigned short* __restrict__ h3b, const float* __restrict__ T,
    unsigned short* __restrict__ accM_out, int c0, int kbase,
    unsigned short* Asm /*128x40*/, unsigned int* Wst /*64x20*/)
{
  const int t    = threadIdx.x;
  const int lane = t & 63, wave = t >> 6;
  const int ml   = lane & 15, q = lane >> 4;
  const int r0   = wave * 32;
  const int ra = t >> 2, qa = t & 3;
  const int kp = t & 15, n4 = (t >> 4) * 4;

  f32x4 acc[2][4];
  #pragma unroll
  for (int i = 0; i < 2; i++)
    #pragma unroll
    for (int j = 0; j < 4; j++) acc[i][j] = (f32x4){0.f, 0.f, 0.f, 0.f};

  const unsigned short* ap = h3b + (size_t)ra * 1024 + kbase + qa * 8;
  const float*          tp = T + (size_t)(kbase + 2 * kp) * 10240 + c0 + n4;
  uint4  va0 = *(const uint4*)ap;
  uint4  va1 = *(const uint4*)(ap + 64 * 1024);
  float4 vw0 = *(const float4*)tp;
  float4 vw1 = *(const float4*)(tp + 10240);

  for (int kt = 0; kt < 16; kt++) {
    *(uint4*)(Asm + ra * 40 + qa * 8)        = va0;
    *(uint4*)(Asm + (ra + 64) * 40 + qa * 8) = va1;
    Wst[(n4 + 0) * 20 + kp] = f2bf(vw0.x) | (f2bf(vw1.x) << 16);
    Wst[(n4 + 1) * 20 + kp] = f2bf(vw0.y) | (f2bf(vw1.y) << 16);
    Wst[(n4 + 2) * 20 + kp] = f2bf(vw0.z) | (f2bf(vw1.z) << 16);
    Wst[(n4 + 3) * 20 + kp] = f2bf(vw0.w) | (f2bf(vw1.w) << 16);
    __syncthreads();
    if (kt < 15) {
      ap += 32;
      tp += (size_t)32 * 10240;
      va0 = *(const uint4*)ap;
      va1 = *(const uint4*)(ap + 64 * 1024);
      vw0 = *(const float4*)tp;
      vw1 = *(const float4*)(tp + 10240);
    }
    bf16x8 a0 = *(const bf16x8*)(Asm + (r0 + ml) * 40 + q * 8);
    bf16x8 a1 = *(const bf16x8*)(Asm + (r0 + 16 + ml) * 40 + q * 8);
    #pragma unroll
    for (int ct = 0; ct < 4; ct++) {
      bf16x8 b = *(const bf16x8*)((const unsigned short*)Wst +
                                  (size_t)((ct * 16 + ml) * 20 + q * 4) * 2);
      acc[0][ct] = __builtin_amdgcn_mfma_f32_16x16x32_bf16(a0, b, acc[0][ct], 0, 0, 0);
      acc[1][ct] = __builtin_amdgcn_mfma_f32_16x16x32_bf16(a1, b, acc[1][ct], 0, 0, 0);
    }
    __syncthreads();
  }

  // C/D layout: col = lane&15, row = (lane>>4)*4 + reg
  #pragma unroll
  for (int rt = 0; rt < 2; rt++)
    #pragma unroll
    for (int ct = 0; ct < 4; ct++) {
      int col = c0 + ct * 16 + ml;
      int row = r0 + rt * 16 + q * 4;
      #pragma unroll
      for (int i = 0; i < 4; i++)
        accM_out[(size_t)(row + i) * 10240 + col] = (unsigned short)f2bf(acc[rt][ct][i]);
    }
}

// K4: gemm4 + per-o pairwise (owner = block completing an o's dependencies)
//     + final dot (owner = block bringing fin counter to 512).
__global__ __launch_bounds__(256, 4) void k4(
    const unsigned short* __restrict__ h3b, const float* __restrict__ T,
    unsigned short* __restrict__ accM, float* __restrict__ feat,
    const float* __restrict__ Wc, const float* __restrict__ bc,
    float* __restrict__ out, unsigned int* __restrict__ ocnt,
    unsigned int* __restrict__ fin)
{
  __shared__ __align__(16) unsigned short Asm[128 * 40];  // 10.0 KB
  __shared__ __align__(16) unsigned int   Wst[64 * 20];   //  5.0 KB
  __shared__ __align__(16) float          Ml[128 * 20];   // 10.0 KB
  __shared__ float parts[4 * 128];                        //  2.0 KB
  __shared__ int n_own, own[4];
  __shared__ unsigned int fin_old;

  const int t   = threadIdx.x;
  const int bid = blockIdx.x;
  const int c0  = (bid >> 1) * 64;
  const int ks  = bid & 1;

  gemm4_ph(h3b, T, accM + (size_t)ks * 128 * 10240, c0, ks * 512, Asm, Wst);

  __threadfence();                 // release accM slice
  __syncthreads();
  if (t == 0) {
    int m = 0;
    const int o_first = c0 / 20, o_last = (c0 + 63) / 20;
    for (int o = o_first; o <= o_last; o++) {
      int tlo = (20 * o) >> 6, thi = (20 * o + 19) >> 6;      // covering coltiles
      unsigned int tgt = 2u * (unsigned int)(thi - tlo + 1);  // x2 K-splits
      unsigned int old = atomicAdd(&ocnt[o], 1u);
      if (old == tgt - 1u) own[m++] = o;
    }
    n_own = m;
  }
  __syncthreads();

  if (n_own > 0) __threadfence();  // acquire other blocks' accM slices

  for (int e = 0; e < n_own; e++) {
    const int o = own[e];
    { // M[:, o, :] = sum of 2 bf16 K-split halves
      int i = t >> 1, kh = (t & 1) * 10;
      const unsigned short* p0 = accM + (size_t)i * 10240 + o * 20 + kh;
      const unsigned short* p1 = p0 + (size_t)128 * 10240;
      #pragma unroll
      for (int k = 0; k < 10; k++)
        Ml[i * 20 + kh + k] = bf2f(p0[k]) + bf2f(p1[k]);
    }
    __syncthreads();
    const int jg = t & 63, istrip = t >> 6;   // 64 j-groups x 4 i-strips of 32
    float mj[2][20];
    #pragma unroll
    for (int c = 0; c < 2; c++) {
      const float* src = Ml + (size_t)(jg * 2 + c) * 20;
      #pragma unroll
      for (int k = 0; k < 20; k++) mj[c][k] = src[k];
    }
    float acc2[2] = {0.f, 0.f};
    for (int ii = 0; ii < 32; ii++) {
      int i = istrip * 32 + ii;
      const float4* m4 = (const float4*)(Ml + (size_t)i * 20);
      float mi[20];
      *(float4*)(mi + 0)  = m4[0]; *(float4*)(mi + 4)  = m4[1];
      *(float4*)(mi + 8)  = m4[2]; *(float4*)(mi + 12) = m4[3];
      *(float4*)(mi + 16) = m4[4];
      #pragma unroll
      for (int c = 0; c < 2; c++) {
        float norm = 0.f;
        #pragma unroll
        for (int k = 0; k < 20; k++) norm += fabsf(mi[k] - mj[c][k]);
        acc2[c] += __expf(-norm);
      }
    }
    #pragma unroll
    for (int c = 0; c < 2; c++) parts[istrip * 128 + jg * 2 + c] = acc2[c];
    __syncthreads();
    if (t < 128) {
      float s = 0.f;
      #pragma unroll
      for (int ih = 0; ih < 4; ih++) s += parts[ih * 128 + t];
      feat[(size_t)t * 1536 + 1024 + o] = s - 1.0f;   // subtract self-term
    }
    __syncthreads();   // protect Ml/parts before next owned o
  }

  if (n_own > 0) {
    __threadfence();               // release feat o-columns
    __syncthreads();
    if (t == 0) fin_old = atomicAdd(fin, (unsigned int)n_own);
    __syncthreads();
    if (fin_old + (unsigned int)n_own == 512u) {
      __threadfence();             // acquire all feat writes
      if (t < 128) {               // final: out[r] = feat[r,:] . Wc + bc
        const float4* fr  = (const float4*)(feat + (size_t)t * 1536);
        const float4* wc4 = (const float4*)Wc;
        float s = 0.f;
        for (int c = 0; c < 384; c++) {
          float4 f = fr[c], w = wc4[c];
          s += f.x * w.x + f.y * w.y + f.z * w.z + f.w * w.w;
        }
        out[t] = s + bc[0];
      }
    }
  }
}

// ---------------------------------------------------------------------------
extern "C" void kernel_launch(void* const* d_in, const int* in_sizes, int n_in,
                              void* d_out, int out_size, void* d_ws, size_t ws_size,
                              hipStream_t stream)
{
  const float* X  = (const float*)d_in[0];
  const float* W1 = (const float*)d_in[1];
  const float* b1 = (const float*)d_in[2];
  const float* W2 = (const float*)d_in[3];
  const float* b2 = (const float*)d_in[4];
  const float* W3 = (const float*)d_in[5];
  const float* b3 = (const float*)d_in[6];
  const float* T  = (const float*)d_in[7];
  const float* Wc = (const float*)d_in[8];
  const float* bc = (const float*)d_in[9];
  char* ws = (char*)d_ws;

  unsigned int*   flags = (unsigned int*)ws;
  unsigned int*   f1    = flags;          // 64
  unsigned int*   f2    = flags + 64;     // 64 (32 used)
  unsigned int*   f3    = flags + 128;    // 64 (32 used)
  unsigned int*   ocnt  = flags + 256;    // 512
  unsigned int*   fin   = flags + 768;    // 1
  float*          P     = (float*)(ws + (size_t)1 * 1024 * 1024);
  unsigned short* accM  = (unsigned short*)(ws + (size_t)10 * 1024 * 1024);
  float*          h1    = (float*)(ws + (size_t)16 * 1024 * 1024);
  float*          h2    = (float*)(ws + (size_t)18 * 1024 * 1024);
  unsigned short* h3b   = (unsigned short*)(ws + (size_t)19 * 1024 * 1024);
  float*          feat  = (float*)(ws + (size_t)20 * 1024 * 1024);
  float*          out   = (float*)d_out;

  hipMemsetAsync(ws, 0, 4096, stream);   // zero all counters

  // L1: h1 = lrelu(X @ W1 + b1)   [128,2048], K=2048, splitK 8
  k_layer<<<dim3(64, 8), 256, 0, stream>>>(X, W1, b1, P, h1, nullptr, f1,
                                           2048, 2048, 256, 8, 2048);
  // L2: h2 = lrelu(h1 @ W2 + b2)  [128,1024], K=2048, splitK 16
  k_layer<<<dim3(32, 16), 256, 0, stream>>>(h1, W2, b2, P, h2, nullptr, f2,
                                            2048, 1024, 128, 16, 1024);
  // L3: feat[:,:1024] = lrelu(h2 @ W3 + b3); h3b = bf16(feat[:,:1024])
  k_layer<<<dim3(32, 8), 256, 0, stream>>>(h2, W3, b3, P, feat, h3b, f3,
                                           1024, 1024, 128, 8, 1536);
  // K4: M = h3 @ T (MFMA, K-split 2) + pairwise + final dot
  k4<<<320, 256, 0, stream>>>(h3b, T, accM, feat, Wc, bc, out, ocnt, fin);
}

// Round 5
// 348.840 us; speedup vs baseline: 2.9436x; 1.2814x over previous
//
#include <hip/hip_runtime.h>
#include <hip/hip_bf16.h>

// ---------------------------------------------------------------------------
// 5 nodes, ZERO device fences (round-4's __threadfence = per-block L2 walk was
// the 179us k4 stall):
//  N0 hipMemsetAsync: flags + H1 + H2 + H3 + M zeroed (7.3 MB, ~1.2 us)
//  N1 gemm_layer: H1 += X @ W1            (split-K 8, float atomicAdd)
//  N2 gemm_layer: H2 += lrelu(H1+b1) @ W2 (split-K 16, inline bias+lrelu in A-staging)
//  N3 gemm_layer: H3 += lrelu(H2+b2) @ W3 (split-K 8)
//  N4 G4: M += lrelu(H3+b3) @ T (bf16 MFMA 16x16x32, split-K 4, f32 atomicAdd)
//        -> per-o owner (flag atomicAdd after __syncthreads vmcnt drain) does
//           pairwise -> featO (agent-scope sc stores); fin-flag completer does
//           final dot (h-part recomputed from H3 inline) -> out.
// Cross-XCD visibility: device atomics at LLC + relaxed agent-scope
// __hip_atomic_load/store (per-access coherent, no buffer_wbl2/inv walks).
// ws layout (bytes):
//   [0, 4096)            ocnt[512] @0, fin @2048
//   [4096, 1052672)      H1  128x2048 f32 (raw, pre-activation)
//   [1052672, 1576960)   H2  128x1024 f32
//   [1576960, 2101248)   H3  128x1024 f32
//   [2101248, 7344128)   M   128x10240 f32 (atomic-accumulated)
//   [8388608, 8650752)   featO 128x512 f32 (o_b part only; fully overwritten)
// ---------------------------------------------------------------------------

typedef __bf16 bf16x8 __attribute__((ext_vector_type(8)));
typedef float  f32x4  __attribute__((ext_vector_type(4)));

static __device__ __forceinline__ unsigned int f2bf(float f) {
  union { float f; unsigned int u; } v; v.f = f;
  unsigned int r = v.u + 0x7FFFu + ((v.u >> 16) & 1u);   // RNE to bf16
  return r >> 16;
}
static __device__ __forceinline__ float lrelu(float x) {
  return x >= 0.0f ? x : 0.01f * x;
}
static __device__ __forceinline__ void fma4(float4& c, float a, const float4& w) {
  c.x = fmaf(a, w.x, c.x); c.y = fmaf(a, w.y, c.y);
  c.z = fmaf(a, w.z, c.z); c.w = fmaf(a, w.w, c.w);
}
// Agent-scope relaxed (sc) accesses: coherent at LLC, no cache walks.
static __device__ __forceinline__ void sc_store_f32(float* p, float v) {
  __hip_atomic_store(p, v, __ATOMIC_RELAXED, __HIP_MEMORY_SCOPE_AGENT);
}
static __device__ __forceinline__ float2 sc_load_f32x2(const float* p) {
  unsigned long long u = __hip_atomic_load((unsigned long long*)p,
                                           __ATOMIC_RELAXED, __HIP_MEMORY_SCOPE_AGENT);
  union { unsigned long long u; float2 f; } v; v.u = u;
  return v.f;
}

// ---------------------------------------------------------------------------
// fp32 layer: H_out += [lrelu(A+abias)] @ W  (atomicAdd output, split-K).
// Block: 256 thr, tile 128x32, micro 4x4, register-prefetch double buffer.
// Grid (N/32, S). abias==nullptr -> A used raw (layer 1).
// ---------------------------------------------------------------------------
__global__ __launch_bounds__(256, 4) void gemm_layer(
    const float* __restrict__ A, const float* __restrict__ abias,
    const float* __restrict__ W, float* __restrict__ H,
    int lda, int N, int kchunk)
{
  __shared__ __align__(16) float As[16 * 128];   // [k][row]
  __shared__ __align__(16) float Ws[16 * 32];    // [k][col]
  const int t     = threadIdx.x;
  const int c0    = blockIdx.x * 32;
  const int kbase = blockIdx.y * kchunk;
  const int rowg  = t >> 3, colg = t & 7;
  const int r_s   = t >> 1, kh_s = (t & 1) * 8;
  const int kw_s  = t >> 4, f_s  = (t & 15) * 2;

  float4 acc[4];
  acc[0] = make_float4(0, 0, 0, 0); acc[1] = make_float4(0, 0, 0, 0);
  acc[2] = make_float4(0, 0, 0, 0); acc[3] = make_float4(0, 0, 0, 0);

  const float* aptr = A + (size_t)r_s * lda + kbase + kh_s;
  const float* wptr = W + (size_t)(kbase + kw_s) * N + c0 + f_s;
  float4 pa0 = *(const float4*)aptr;
  float4 pa1 = *(const float4*)(aptr + 4);
  float4 pb0 = make_float4(0, 0, 0, 0), pb1 = make_float4(0, 0, 0, 0);
  if (abias) {
    pb0 = *(const float4*)(abias + kbase + kh_s);
    pb1 = *(const float4*)(abias + kbase + kh_s + 4);
  }
  float2 pw = *(const float2*)wptr;

  for (int kt = 0; kt < kchunk; kt += 16) {
    float4 a0 = pa0, a1 = pa1;
    if (abias) {
      a0.x = lrelu(a0.x + pb0.x); a0.y = lrelu(a0.y + pb0.y);
      a0.z = lrelu(a0.z + pb0.z); a0.w = lrelu(a0.w + pb0.w);
      a1.x = lrelu(a1.x + pb1.x); a1.y = lrelu(a1.y + pb1.y);
      a1.z = lrelu(a1.z + pb1.z); a1.w = lrelu(a1.w + pb1.w);
    }
    As[(kh_s + 0) * 128 + r_s] = a0.x; As[(kh_s + 1) * 128 + r_s] = a0.y;
    As[(kh_s + 2) * 128 + r_s] = a0.z; As[(kh_s + 3) * 128 + r_s] = a0.w;
    As[(kh_s + 4) * 128 + r_s] = a1.x; As[(kh_s + 5) * 128 + r_s] = a1.y;
    As[(kh_s + 6) * 128 + r_s] = a1.z; As[(kh_s + 7) * 128 + r_s] = a1.w;
    *(float2*)(Ws + kw_s * 32 + f_s) = pw;
    __syncthreads();
    if (kt + 16 < kchunk) {
      aptr += 16;
      wptr += (size_t)16 * N;
      pa0 = *(const float4*)aptr;
      pa1 = *(const float4*)(aptr + 4);
      if (abias) {
        pb0 = *(const float4*)(abias + kbase + kt + 16 + kh_s);
        pb1 = *(const float4*)(abias + kbase + kt + 16 + kh_s + 4);
      }
      pw = *(const float2*)wptr;
    }
    #pragma unroll
    for (int k = 0; k < 16; k++) {
      float4 w = *(const float4*)(Ws + k * 32 + colg * 4);
      float4 a = *(const float4*)(As + k * 128 + rowg * 4);
      fma4(acc[0], a.x, w); fma4(acc[1], a.y, w);
      fma4(acc[2], a.z, w); fma4(acc[3], a.w, w);
    }
    __syncthreads();
  }

  float* op = H + (size_t)(rowg * 4) * N + c0 + colg * 4;
  #pragma unroll
  for (int j = 0; j < 4; j++) {
    atomicAdd(op + (size_t)j * N + 0, acc[j].x);
    atomicAdd(op + (size_t)j * N + 1, acc[j].y);
    atomicAdd(op + (size_t)j * N + 2, acc[j].z);
    atomicAdd(op + (size_t)j * N + 3, acc[j].w);
  }
}

// ---------------------------------------------------------------------------
// G4: M += lrelu(H3+b3)@T (bf16 MFMA, split-K 4, atomicAdd f32) + owner
// pairwise + completer final dot. Grid 640: coltile = bid>>2, ks = bid&3.
// ---------------------------------------------------------------------------
__global__ __launch_bounds__(256, 4) void g4(
    const float* __restrict__ H3, const float* __restrict__ b3,
    const float* __restrict__ T, float* __restrict__ M,
    float* __restrict__ featO, const float* __restrict__ Wc,
    const float* __restrict__ bc, float* __restrict__ out,
    unsigned int* __restrict__ ocnt, unsigned int* __restrict__ fin)
{
  __shared__ __align__(16) unsigned short Asm[128 * 40];  // 10.0 KB, [row][k] pad 40
  __shared__ __align__(16) unsigned int   Wst[64 * 20];   //  5.0 KB, [n][kpair]
  __shared__ __align__(16) float          Ml[128 * 20];   // 10.0 KB
  __shared__ float parts[4 * 128];                        //  2.0 KB (reused as red)
  __shared__ int n_own, own[4];
  __shared__ unsigned int fin_old;

  const int t    = threadIdx.x;
  const int c0   = (blockIdx.x >> 2) * 64;
  const int kbase = (blockIdx.x & 3) * 256;
  const int lane = t & 63, wave = t >> 6;
  const int ml   = lane & 15, q = lane >> 4;
  const int r0   = wave * 32;
  const int ra = t >> 2, qa = t & 3;            // A staging: rows ra, ra+64; k qa*8..+8
  const int kp = t & 15, n4 = (t >> 4) * 4;     // T staging

  f32x4 acc[2][4];
  #pragma unroll
  for (int i = 0; i < 2; i++)
    #pragma unroll
    for (int j = 0; j < 4; j++) acc[i][j] = (f32x4){0.f, 0.f, 0.f, 0.f};

  const float* ap = H3 + (size_t)ra * 1024 + kbase + qa * 8;
  const float* tp = T + (size_t)(kbase + 2 * kp) * 10240 + c0 + n4;
  float4 va0 = *(const float4*)ap,             va1 = *(const float4*)(ap + 4);
  float4 va2 = *(const float4*)(ap + 64*1024), va3 = *(const float4*)(ap + 64*1024 + 4);
  float4 vb0 = *(const float4*)(b3 + kbase + qa * 8);
  float4 vb1 = *(const float4*)(b3 + kbase + qa * 8 + 4);
  float4 vw0 = *(const float4*)tp;
  float4 vw1 = *(const float4*)(tp + 10240);

  for (int kt = 0; kt < 8; kt++) {
    { // A: lrelu(H3+b3) -> bf16 pairs
      uint4 u;
      u.x = f2bf(lrelu(va0.x + vb0.x)) | (f2bf(lrelu(va0.y + vb0.y)) << 16);
      u.y = f2bf(lrelu(va0.z + vb0.z)) | (f2bf(lrelu(va0.w + vb0.w)) << 16);
      u.z = f2bf(lrelu(va1.x + vb1.x)) | (f2bf(lrelu(va1.y + vb1.y)) << 16);
      u.w = f2bf(lrelu(va1.z + vb1.z)) | (f2bf(lrelu(va1.w + vb1.w)) << 16);
      *(uint4*)(Asm + ra * 40 + qa * 8) = u;
      u.x = f2bf(lrelu(va2.x + vb0.x)) | (f2bf(lrelu(va2.y + vb0.y)) << 16);
      u.y = f2bf(lrelu(va2.z + vb0.z)) | (f2bf(lrelu(va2.w + vb0.w)) << 16);
      u.z = f2bf(lrelu(va3.x + vb1.x)) | (f2bf(lrelu(va3.y + vb1.y)) << 16);
      u.w = f2bf(lrelu(va3.z + vb1.z)) | (f2bf(lrelu(va3.w + vb1.w)) << 16);
      *(uint4*)(Asm + (ra + 64) * 40 + qa * 8) = u;
    }
    Wst[(n4 + 0) * 20 + kp] = f2bf(vw0.x) | (f2bf(vw1.x) << 16);
    Wst[(n4 + 1) * 20 + kp] = f2bf(vw0.y) | (f2bf(vw1.y) << 16);
    Wst[(n4 + 2) * 20 + kp] = f2bf(vw0.z) | (f2bf(vw1.z) << 16);
    Wst[(n4 + 3) * 20 + kp] = f2bf(vw0.w) | (f2bf(vw1.w) << 16);
    __syncthreads();
    if (kt < 7) {
      ap += 32;
      tp += (size_t)32 * 10240;
      va0 = *(const float4*)ap;             va1 = *(const float4*)(ap + 4);
      va2 = *(const float4*)(ap + 64*1024); va3 = *(const float4*)(ap + 64*1024 + 4);
      vb0 = *(const float4*)(b3 + kbase + (kt+1)*32 + qa * 8);
      vb1 = *(const float4*)(b3 + kbase + (kt+1)*32 + qa * 8 + 4);
      vw0 = *(const float4*)tp;
      vw1 = *(const float4*)(tp + 10240);
    }
    bf16x8 a0 = *(const bf16x8*)(Asm + (r0 + ml) * 40 + q * 8);
    bf16x8 a1 = *(const bf16x8*)(Asm + (r0 + 16 + ml) * 40 + q * 8);
    #pragma unroll
    for (int ct = 0; ct < 4; ct++) {
      bf16x8 b = *(const bf16x8*)((const unsigned short*)Wst +
                                  (size_t)((ct * 16 + ml) * 20 + q * 4) * 2);
      acc[0][ct] = __builtin_amdgcn_mfma_f32_16x16x32_bf16(a0, b, acc[0][ct], 0, 0, 0);
      acc[1][ct] = __builtin_amdgcn_mfma_f32_16x16x32_bf16(a1, b, acc[1][ct], 0, 0, 0);
    }
    __syncthreads();
  }

  // M += acc (device atomics at LLC; C/D: col=lane&15, row=(lane>>4)*4+reg)
  #pragma unroll
  for (int rt = 0; rt < 2; rt++)
    #pragma unroll
    for (int ct = 0; ct < 4; ct++) {
      int col = c0 + ct * 16 + ml;
      int row = r0 + rt * 16 + q * 4;
      #pragma unroll
      for (int i = 0; i < 4; i++)
        atomicAdd(&M[(size_t)(row + i) * 10240 + col], acc[rt][ct][i]);
    }

  __syncthreads();   // compiler drains vmcnt per wave -> all M atomics retired
  if (t == 0) {
    int m = 0;
    const int o_first = c0 / 20;
    for (int e = 0; e < 4; e++) {
      int o = o_first + e;
      int tlo = (20 * o) >> 6, thi = (20 * o + 19) >> 6;
      unsigned int tgt = 4u * (unsigned int)(thi - tlo + 1);
      unsigned int old = atomicAdd(&ocnt[o], 1u);
      if (old == tgt - 1u) own[m++] = o;
    }
    n_own = m;
  }
  __syncthreads();

  for (int e = 0; e < n_own; e++) {
    const int o = own[e];
    { // Ml = M[:, o*20 .. +20] (sc loads: fresh from LLC)
      int i = t >> 1, kh = (t & 1) * 10;
      const float* mp = M + (size_t)i * 10240 + o * 20 + kh;
      #pragma unroll
      for (int k = 0; k < 5; k++) {
        float2 v = sc_load_f32x2(mp + 2 * k);
        Ml[i * 20 + kh + 2 * k]     = v.x;
        Ml[i * 20 + kh + 2 * k + 1] = v.y;
      }
    }
    __syncthreads();
    const int jg = t & 63, istrip = t >> 6;   // 64 j-groups(2/thr) x 4 i-strips(32)
    float mj[2][20];
    #pragma unroll
    for (int c = 0; c < 2; c++) {
      const float* src = Ml + (size_t)(jg * 2 + c) * 20;
      #pragma unroll
      for (int k = 0; k < 20; k++) mj[c][k] = src[k];
    }
    float a2[2] = {0.f, 0.f};
    for (int ii = 0; ii < 32; ii++) {
      int i = istrip * 32 + ii;
      const float4* m4 = (const float4*)(Ml + (size_t)i * 20);
      float mi[20];
      *(float4*)(mi + 0)  = m4[0]; *(float4*)(mi + 4)  = m4[1];
      *(float4*)(mi + 8)  = m4[2]; *(float4*)(mi + 12) = m4[3];
      *(float4*)(mi + 16) = m4[4];
      #pragma unroll
      for (int c = 0; c < 2; c++) {
        float norm = 0.f;
        #pragma unroll
        for (int k = 0; k < 20; k++) norm += fabsf(mi[k] - mj[c][k]);
        a2[c] += __expf(-norm);
      }
    }
    #pragma unroll
    for (int c = 0; c < 2; c++) parts[istrip * 128 + jg * 2 + c] = a2[c];
    __syncthreads();
    if (t < 128) {
      float s = 0.f;
      #pragma unroll
      for (int ih = 0; ih < 4; ih++) s += parts[ih * 128 + t];
      sc_store_f32(&featO[(size_t)t * 512 + o], s - 1.0f);  // minus self-term
    }
    __syncthreads();
  }

  if (n_own > 0) {
    __syncthreads();               // drain featO sc stores (all waves)
    if (t == 0) fin_old = atomicAdd(fin, (unsigned int)n_own);
    __syncthreads();
    if (fin_old + (unsigned int)n_own == 512u) {
      // final: out[r] = [lrelu(H3[r]+b3) | featO[r]] . Wc + bc
      const int row = t >> 1, hh = t & 1;
      float s = 0.f;
      const float4* h3r = (const float4*)(H3 + (size_t)row * 1024 + hh * 512);
      const float4* b3v = (const float4*)(b3 + hh * 512);
      const float4* wcv = (const float4*)(Wc + hh * 512);
      for (int c = 0; c < 128; c++) {
        float4 h = h3r[c], b = b3v[c], w = wcv[c];
        s += lrelu(h.x + b.x) * w.x + lrelu(h.y + b.y) * w.y +
             lrelu(h.z + b.z) * w.z + lrelu(h.w + b.w) * w.w;
      }
      const float*  fo = featO + (size_t)row * 512 + hh * 256;
      const float2* wo = (const float2*)(Wc + 1024 + hh * 256);
      for (int c = 0; c < 128; c++) {
        float2 f = sc_load_f32x2(fo + 2 * c);
        float2 w = wo[c];
        s += f.x * w.x + f.y * w.y;
      }
      parts[t] = s;
      __syncthreads();
      if ((t & 1) == 0) out[row] = parts[t] + parts[t + 1] + bc[0];
    }
  }
}

// ---------------------------------------------------------------------------
extern "C" void kernel_launch(void* const* d_in, const int* in_sizes, int n_in,
                              void* d_out, int out_size, void* d_ws, size_t ws_size,
                              hipStream_t stream)
{
  const float* X  = (const float*)d_in[0];
  const float* W1 = (const float*)d_in[1];
  const float* b1 = (const float*)d_in[2];
  const float* W2 = (const float*)d_in[3];
  const float* b2 = (const float*)d_in[4];
  const float* W3 = (const float*)d_in[5];
  const float* b3 = (const float*)d_in[6];
  const float* T  = (const float*)d_in[7];
  const float* Wc = (const float*)d_in[8];
  const float* bc = (const float*)d_in[9];
  char* ws = (char*)d_ws;

  unsigned int* ocnt  = (unsigned int*)ws;                  // 512
  unsigned int* fin   = (unsigned int*)(ws + 2048);         // 1
  float*        H1    = (float*)(ws + 4096);                // 128x2048
  float*        H2    = (float*)(ws + 1052672);             // 128x1024
  float*        H3    = (float*)(ws + 1576960);             // 128x1024
  float*        M     = (float*)(ws + 2101248);             // 128x10240
  float*        featO = (float*)(ws + 8388608);             // 128x512
  float*        out   = (float*)d_out;

  // zero flags + H1 + H2 + H3 + M in one node
  hipMemsetAsync(ws, 0, 7344128, stream);

  // L1: H1 = X @ W1                      (raw A)
  gemm_layer<<<dim3(64, 8), 256, 0, stream>>>(X, nullptr, W1, H1, 2048, 2048, 256);
  // L2: H2 = lrelu(H1+b1) @ W2
  gemm_layer<<<dim3(32, 16), 256, 0, stream>>>(H1, b1, W2, H2, 2048, 1024, 128);
  // L3: H3 = lrelu(H2+b2) @ W3
  gemm_layer<<<dim3(32, 8), 256, 0, stream>>>(H2, b2, W3, H3, 1024, 1024, 128);
  // G4: M = lrelu(H3+b3) @ T + pairwise + final
  g4<<<640, 256, 0, stream>>>(H3, b3, T, M, featO, Wc, bc, out, ocnt, fin);
}

// Round 7
// 289.226 us; speedup vs baseline: 3.5503x; 1.2061x over previous
//
#include <hip/hip_runtime.h>
#include <hip/hip_bf16.h>
#include <hip/hip_fp16.h>

// ---------------------------------------------------------------------------
// 5 nodes; atomics ONLY as flags (~500/call, round-5's 10.5M tensor-atomicAdd
// flood removed — it serialized at the coherence point):
//  N0 memset 1024 B of flags
//  N1-N3 k_layer: split-K fp32 gemm -> sc(write-through) 64-bit partial stores
//        -> flag atomicAdd -> last block reduces + bias + lrelu -> h (plain)
//  N4 g4: 128 blocks, col-tile 80 = exactly 4 o's, full K=1024 -> M stays in
//        registers/LDS (never global!) -> fused pairwise (packed fp16) ->
//        featO sc stores -> fin-flag completer does final dot -> out.
// ws layout (bytes):
//   [0, 1024)        flags: f1[64]@0, f2[32]@256, f3[32]@384, fin@512
//   [4096, 8.4M)     P: split-K partials (max 16x128x1024 or 8x128x2048 f32)
//   [12M, 13M)       h1 128x2048 f32 (activated)
//   [14M, 14.5M)     h2 128x1024 f32
//   [15M, 15.5M)     h3 128x1024 f32
//   [16M, 16.25M)    featO 128x512 f32
// ---------------------------------------------------------------------------

typedef __bf16  bf16x8 __attribute__((ext_vector_type(8)));
typedef float   f32x4  __attribute__((ext_vector_type(4)));
typedef __fp16  h2     __attribute__((ext_vector_type(2)));   // matches cvt_pkrtz

static __device__ __forceinline__ unsigned int f2bf(float f) {
  union { float f; unsigned int u; } v; v.f = f;
  unsigned int r = v.u + 0x7FFFu + ((v.u >> 16) & 1u);   // RNE to bf16
  return r >> 16;
}
static __device__ __forceinline__ float lrelu(float x) {
  return x >= 0.0f ? x : 0.01f * x;
}
static __device__ __forceinline__ void fma4(float4& c, float a, const float4& w) {
  c.x = fmaf(a, w.x, c.x); c.y = fmaf(a, w.y, c.y);
  c.z = fmaf(a, w.z, c.z); c.w = fmaf(a, w.w, c.w);
}
// Agent-scope relaxed accesses: write-through/coherent at LLC, no RMW, no walks.
static __device__ __forceinline__ void sc_store_f32(float* p, float v) {
  __hip_atomic_store(p, v, __ATOMIC_RELAXED, __HIP_MEMORY_SCOPE_AGENT);
}
static __device__ __forceinline__ void sc_store_f32x2(float* p, float x, float y) {
  union { float2 f; unsigned long long u; } v; v.f = make_float2(x, y);
  __hip_atomic_store((unsigned long long*)p, v.u, __ATOMIC_RELAXED,
                     __HIP_MEMORY_SCOPE_AGENT);
}
static __device__ __forceinline__ float2 sc_load_f32x2(const float* p) {
  unsigned long long u = __hip_atomic_load((const unsigned long long*)p,
                                           __ATOMIC_RELAXED, __HIP_MEMORY_SCOPE_AGENT);
  union { unsigned long long u; float2 f; } v; v.u = u;
  return v.f;
}
static __device__ __forceinline__ h2 habs2(h2 v) {
  union { h2 h; unsigned int u; } x; x.h = v; x.u &= 0x7FFF7FFFu; return x.h;
}

// ---------------------------------------------------------------------------
// fp32 layer: split-K gemm (tile 128x32, micro 4x4, reg double-buffer) ->
// sc partial stores -> flag -> last block: reduce + bias + lrelu -> outF.
// Grid (N/32, S).
// ---------------------------------------------------------------------------
__global__ __launch_bounds__(256, 4) void k_layer(
    const float* __restrict__ A, const float* __restrict__ W,
    const float* __restrict__ bias, float* __restrict__ P,
    float* __restrict__ outF, unsigned int* __restrict__ flag,
    int lda, int N, int kchunk, int S)
{
  __shared__ __align__(16) float As[16 * 128];   // [k][row]
  __shared__ __align__(16) float Ws[16 * 32];    // [k][col]
  __shared__ unsigned int sOld;
  const int t     = threadIdx.x;
  const int c0    = blockIdx.x * 32;
  const int kbase = blockIdx.y * kchunk;
  const int rowg  = t >> 3, colg = t & 7;
  const int r_s   = t >> 1, kh_s = (t & 1) * 8;
  const int kw_s  = t >> 4, f_s  = (t & 15) * 2;

  float4 acc[4];
  acc[0] = make_float4(0, 0, 0, 0); acc[1] = make_float4(0, 0, 0, 0);
  acc[2] = make_float4(0, 0, 0, 0); acc[3] = make_float4(0, 0, 0, 0);

  const float* aptr = A + (size_t)r_s * lda + kbase + kh_s;
  const float* wptr = W + (size_t)(kbase + kw_s) * N + c0 + f_s;
  float4 pa0 = *(const float4*)aptr;
  float4 pa1 = *(const float4*)(aptr + 4);
  float2 pw  = *(const float2*)wptr;

  for (int kt = 0; kt < kchunk; kt += 16) {
    As[(kh_s + 0) * 128 + r_s] = pa0.x; As[(kh_s + 1) * 128 + r_s] = pa0.y;
    As[(kh_s + 2) * 128 + r_s] = pa0.z; As[(kh_s + 3) * 128 + r_s] = pa0.w;
    As[(kh_s + 4) * 128 + r_s] = pa1.x; As[(kh_s + 5) * 128 + r_s] = pa1.y;
    As[(kh_s + 6) * 128 + r_s] = pa1.z; As[(kh_s + 7) * 128 + r_s] = pa1.w;
    *(float2*)(Ws + kw_s * 32 + f_s) = pw;
    __syncthreads();
    if (kt + 16 < kchunk) {
      aptr += 16;
      wptr += (size_t)16 * N;
      pa0 = *(const float4*)aptr;
      pa1 = *(const float4*)(aptr + 4);
      pw  = *(const float2*)wptr;
    }
    #pragma unroll
    for (int k = 0; k < 16; k++) {
      float4 w = *(const float4*)(Ws + k * 32 + colg * 4);
      float4 a = *(const float4*)(As + k * 128 + rowg * 4);
      fma4(acc[0], a.x, w); fma4(acc[1], a.y, w);
      fma4(acc[2], a.z, w); fma4(acc[3], a.w, w);
    }
    __syncthreads();
  }

  // write partials (write-through 64-bit stores, no RMW)
  float* op = P + (size_t)blockIdx.y * 128 * N + (size_t)(rowg * 4) * N + c0 + colg * 4;
  #pragma unroll
  for (int j = 0; j < 4; j++) {
    sc_store_f32x2(op + (size_t)j * N,     acc[j].x, acc[j].y);
    sc_store_f32x2(op + (size_t)j * N + 2, acc[j].z, acc[j].w);
  }
  __syncthreads();                    // vmcnt(0): stores ack'd at LLC
  if (t == 0) sOld = atomicAdd(&flag[blockIdx.x], 1u);
  __syncthreads();

  if (sOld == (unsigned int)(S - 1)) {
    // last arriver: reduce S partials for this 32-col tile
    const int row = t >> 1;
    const int cb  = c0 + (t & 1) * 16;
    float4 r[4];
    r[0] = make_float4(0, 0, 0, 0); r[1] = make_float4(0, 0, 0, 0);
    r[2] = make_float4(0, 0, 0, 0); r[3] = make_float4(0, 0, 0, 0);
    for (int s2 = 0; s2 < S; s2++) {
      const float* p = P + (size_t)s2 * 128 * N + (size_t)row * N + cb;
      #pragma unroll
      for (int j = 0; j < 4; j++) {
        float2 a = sc_load_f32x2(p + 4 * j);
        float2 b = sc_load_f32x2(p + 4 * j + 2);
        r[j].x += a.x; r[j].y += a.y; r[j].z += b.x; r[j].w += b.y;
      }
    }
    #pragma unroll
    for (int j = 0; j < 4; j++) {
      float4 b = *(const float4*)(bias + cb + 4 * j);
      float4 o;
      o.x = lrelu(r[j].x + b.x); o.y = lrelu(r[j].y + b.y);
      o.z = lrelu(r[j].z + b.z); o.w = lrelu(r[j].w + b.w);
      *(float4*)(outF + (size_t)row * N + cb + 4 * j) = o;
    }
  }
}

// ---------------------------------------------------------------------------
// g4: 128 blocks x 256 thr. Block b: M[:, 80b..80b+79] = h3 @ T (full K=1024,
// bf16 MFMA 16x16x32, K-tile 64) kept in regs -> LDS -> pairwise on o's
// 4b..4b+3 (packed fp16) -> featO (sc) -> fin completer final dot -> out.
// ---------------------------------------------------------------------------
__global__ __launch_bounds__(256, 2) void g4(
    const float* __restrict__ h3, const float* __restrict__ T,
    float* __restrict__ featO, const float* __restrict__ Wc,
    const float* __restrict__ bc, float* __restrict__ out,
    unsigned int* __restrict__ fin)
{
  __shared__ __align__(16) char smem[47104];
  unsigned short* Asm = (unsigned short*)smem;            // [128][72] bf16 = 18432 B
  unsigned int*   Wst = (unsigned int*)(smem + 18432);    // [2][80][20] dw = 12800 B
  float*          Mlf = (float*)smem;                     // [128][84] f32 = 43008 B (aliases gemm bufs)
  float*          parts = (float*)(smem + 43008);         // [8][128] f32 = 4096 B
  __shared__ unsigned int fin_old;

  const int t    = threadIdx.x;
  const int b    = blockIdx.x;
  const int c0   = b * 80;
  const int lane = t & 63, wave = t >> 6;
  const int ml   = lane & 15, q = lane >> 4;
  const int r0   = wave * 32;
  // staging assignments
  const int ar = t >> 1, ah = t & 1;              // A: row, 32-k half
  const int kpg = t >> 3;                         // T: 32 k-pair groups
  const int tks = kpg >> 4, tkp = kpg & 15;
  const int tn0 = (t & 7) * 10;                   // T: 10-col chunk

  f32x4 acc[2][5];
  #pragma unroll
  for (int i = 0; i < 2; i++)
    #pragma unroll
    for (int j = 0; j < 5; j++) acc[i][j] = (f32x4){0.f, 0.f, 0.f, 0.f};

  const float* ap = h3 + (size_t)ar * 1024 + ah * 32;
  const float* tp = T + (size_t)(tks * 32 + 2 * tkp) * 10240 + c0 + tn0;
  float4 pa[8];
  float2 pt0[5], pt1[5];
  #pragma unroll
  for (int i = 0; i < 8; i++) pa[i] = *(const float4*)(ap + 4 * i);
  #pragma unroll
  for (int i = 0; i < 5; i++) {
    pt0[i] = *(const float2*)(tp + 2 * i);
    pt1[i] = *(const float2*)(tp + 10240 + 2 * i);
  }

  for (int kt = 0; kt < 16; kt++) {
    { // stage A: f32 -> bf16, rows x 64k, pad stride 72
      unsigned short* adst = Asm + ar * 72 + ah * 32;
      #pragma unroll
      for (int jj = 0; jj < 4; jj++) {
        uint4 u;
        u.x = f2bf(pa[2*jj].x)   | (f2bf(pa[2*jj].y)   << 16);
        u.y = f2bf(pa[2*jj].z)   | (f2bf(pa[2*jj].w)   << 16);
        u.z = f2bf(pa[2*jj+1].x) | (f2bf(pa[2*jj+1].y) << 16);
        u.w = f2bf(pa[2*jj+1].z) | (f2bf(pa[2*jj+1].w) << 16);
        *(uint4*)(adst + jj * 8) = u;
      }
    }
    { // stage T: pack k-pairs
      #pragma unroll
      for (int j = 0; j < 5; j++) {
        Wst[(tks * 80 + tn0 + 2*j)     * 20 + tkp] = f2bf(pt0[j].x) | (f2bf(pt1[j].x) << 16);
        Wst[(tks * 80 + tn0 + 2*j + 1) * 20 + tkp] = f2bf(pt0[j].y) | (f2bf(pt1[j].y) << 16);
      }
    }
    __syncthreads();
    if (kt < 15) {   // register prefetch of next K-tile
      ap += 64;
      tp += (size_t)64 * 10240;
      #pragma unroll
      for (int i = 0; i < 8; i++) pa[i] = *(const float4*)(ap + 4 * i);
      #pragma unroll
      for (int i = 0; i < 5; i++) {
        pt0[i] = *(const float2*)(tp + 2 * i);
        pt1[i] = *(const float2*)(tp + 10240 + 2 * i);
      }
    }
    #pragma unroll
    for (int ks = 0; ks < 2; ks++) {
      bf16x8 a0 = *(const bf16x8*)(Asm + (r0 + ml) * 72 + ks * 32 + q * 8);
      bf16x8 a1 = *(const bf16x8*)(Asm + (r0 + 16 + ml) * 72 + ks * 32 + q * 8);
      #pragma unroll
      for (int nt = 0; nt < 5; nt++) {
        bf16x8 bf = *(const bf16x8*)((const unsigned short*)Wst +
                      (size_t)((ks * 80 + nt * 16 + ml) * 20 + q * 4) * 2);
        acc[0][nt] = __builtin_amdgcn_mfma_f32_16x16x32_bf16(a0, bf, acc[0][nt], 0, 0, 0);
        acc[1][nt] = __builtin_amdgcn_mfma_f32_16x16x32_bf16(a1, bf, acc[1][nt], 0, 0, 0);
      }
    }
    __syncthreads();
  }

  // acc -> Mlf[row][col], stride 84 (C/D: col=lane&15, row=(lane>>4)*4+reg)
  #pragma unroll
  for (int rt = 0; rt < 2; rt++)
    #pragma unroll
    for (int nt = 0; nt < 5; nt++)
      #pragma unroll
      for (int i = 0; i < 4; i++)
        Mlf[(r0 + rt * 16 + q * 4 + i) * 84 + nt * 16 + ml] = acc[rt][nt][i];
  __syncthreads();

  // pairwise on o's 4b..4b+3: 32 j-groups (4 j each) x 8 i-strips (16 i each)
  const int jg = t & 31, istrip = t >> 5;
  for (int e = 0; e < 4; e++) {
    h2 mj[4][10];
    #pragma unroll
    for (int c = 0; c < 4; c++) {
      const float2* src = (const float2*)(Mlf + (size_t)(jg * 4 + c) * 84 + e * 20);
      #pragma unroll
      for (int d = 0; d < 10; d++) {
        float2 v = src[d];
        mj[c][d] = __builtin_amdgcn_cvt_pkrtz(v.x, v.y);
      }
    }
    float a4[4] = {0.f, 0.f, 0.f, 0.f};
    for (int ii = 0; ii < 16; ii++) {
      const int i = istrip * 16 + ii;
      const float2* mrow = (const float2*)(Mlf + (size_t)i * 84 + e * 20);
      h2 mih[10];
      #pragma unroll
      for (int d = 0; d < 10; d++) {
        float2 v = mrow[d];
        mih[d] = __builtin_amdgcn_cvt_pkrtz(v.x, v.y);
      }
      #pragma unroll
      for (int c = 0; c < 4; c++) {
        h2 npk = habs2(mih[0] - mj[c][0]);
        #pragma unroll
        for (int d = 1; d < 10; d++) npk += habs2(mih[d] - mj[c][d]);
        float norm = (float)npk[0] + (float)npk[1];
        a4[c] += __expf(-norm);
      }
    }
    #pragma unroll
    for (int c = 0; c < 4; c++) parts[istrip * 128 + jg * 4 + c] = a4[c];
    __syncthreads();
    if (t < 128) {
      float s = 0.f;
      #pragma unroll
      for (int ih = 0; ih < 8; ih++) s += parts[ih * 128 + t];
      sc_store_f32(&featO[(size_t)t * 512 + b * 4 + e], s - 1.0f);  // minus self
    }
    __syncthreads();
  }

  // completer: final dot  out[r] = [h3[r] | featO[r]] . Wc + bc
  if (t == 0) fin_old = atomicAdd(fin, 1u);
  __syncthreads();
  if (fin_old == 127u) {
    const int row = t >> 1, hh = t & 1;
    float s = 0.f;
    const float4* hr = (const float4*)(h3 + (size_t)row * 1024 + hh * 512);
    const float4* wv = (const float4*)(Wc + hh * 512);
    for (int c = 0; c < 128; c++) {
      float4 h = hr[c], w = wv[c];
      s += h.x * w.x + h.y * w.y + h.z * w.z + h.w * w.w;
    }
    const float*  fo = featO + (size_t)row * 512 + hh * 256;
    const float2* wo = (const float2*)(Wc + 1024 + hh * 256);
    for (int c = 0; c < 128; c++) {
      float2 f = sc_load_f32x2(fo + 2 * c);
      float2 w = wo[c];
      s += f.x * w.x + f.y * w.y;
    }
    parts[t] = s;
    __syncthreads();
    if ((t & 1) == 0) out[row] = parts[t] + parts[t + 1] + bc[0];
  }
}

// ---------------------------------------------------------------------------
extern "C" void kernel_launch(void* const* d_in, const int* in_sizes, int n_in,
                              void* d_out, int out_size, void* d_ws, size_t ws_size,
                              hipStream_t stream)
{
  const float* X  = (const float*)d_in[0];
  const float* W1 = (const float*)d_in[1];
  const float* b1 = (const float*)d_in[2];
  const float* W2 = (const float*)d_in[3];
  const float* b2 = (const float*)d_in[4];
  const float* W3 = (const float*)d_in[5];
  const float* b3 = (const float*)d_in[6];
  const float* T  = (const float*)d_in[7];
  const float* Wc = (const float*)d_in[8];
  const float* bc = (const float*)d_in[9];
  char* ws = (char*)d_ws;

  unsigned int* f1    = (unsigned int*)ws;            // 64
  unsigned int* f2    = (unsigned int*)(ws + 256);    // 32
  unsigned int* f3    = (unsigned int*)(ws + 384);    // 32
  unsigned int* fin   = (unsigned int*)(ws + 512);    // 1
  float*        P     = (float*)(ws + 4096);
  float*        h1    = (float*)(ws + (size_t)12 * 1024 * 1024);
  float*        h2    = (float*)(ws + (size_t)14 * 1024 * 1024);
  float*        h3    = (float*)(ws + (size_t)15 * 1024 * 1024);
  float*        featO = (float*)(ws + (size_t)16 * 1024 * 1024);
  float*        out   = (float*)d_out;

  (void)hipMemsetAsync(ws, 0, 1024, stream);   // flags only

  // L1: h1 = lrelu(X @ W1 + b1)   K=2048, splitK 8
  k_layer<<<dim3(64, 8), 256, 0, stream>>>(X, W1, b1, P, h1, f1, 2048, 2048, 256, 8);
  // L2: h2 = lrelu(h1 @ W2 + b2)  K=2048, splitK 16
  k_layer<<<dim3(32, 16), 256, 0, stream>>>(h1, W2, b2, P, h2, f2, 2048, 1024, 128, 16);
  // L3: h3 = lrelu(h2 @ W3 + b3)  K=1024, splitK 8
  k_layer<<<dim3(32, 8), 256, 0, stream>>>(h2, W3, b3, P, h3, f3, 1024, 1024, 128, 8);
  // G4: M = h3 @ T (per-block local) + pairwise + final dot
  g4<<<128, 256, 0, stream>>>(h3, T, featO, Wc, bc, out, fin);
}